// Round 5
// baseline (126.243 us; speedup 1.0000x reference)
//
#include <hip/hip_runtime.h>
#include <hip/hip_bf16.h>

// MACE-like GNN on MI355X — MFMA + prep-kernel (pre-baked bf16 W2 fragments,
// transposed ws/wv, 1/127 folded into W2).
// B=32, N=128, F=64, N_RBF=8, H_R=64, L=2.
// v workspace layout: [node][f][4] (float4 loads in phase C).

#define NN 128
#define BB 32
#define FF 64

using f32x4  = __attribute__((ext_vector_type(4))) float;
using short8 = __attribute__((ext_vector_type(8))) short;

__device__ __forceinline__ unsigned short f2bf(float x) {
    unsigned int u = __float_as_uint(x);
    u += 0x7fff + ((u >> 16) & 1);          // RNE
    return (unsigned short)(u >> 16);
}
__device__ __forceinline__ unsigned short f2bf_fast(float x) {
    return (unsigned short)((__float_as_uint(x) + 0x8000u) >> 16);
}

// -------------------- prep: bake weights into fast layouts -----------------
// w2frag: [layer][wave][nt][ks][lane][e]  bf16, scaled by 1/127
// wT:     [layer][m(0=ws,1=wv)][g][ff]    f32 transposed
__global__ __launch_bounds__(256) void prep_kernel(
    const float* __restrict__ w2,    // [2][64][192]
    const float* __restrict__ ws,    // [2][64][64]
    const float* __restrict__ wv,    // [2][64][64]
    short* __restrict__ w2frag,      // [2][4][3][2][64][8] = 24576 shorts
    float* __restrict__ wT)          // [2][2][64][64]      = 16384 floats
{
    const int tid = blockIdx.x * 256 + threadIdx.x;
    const int NFRAG = 24576;
    if (tid < NFRAG) {
        const int e  = tid & 7;
        const int l  = (tid >> 3) & 63;
        const int ks = (tid >> 9) & 1;
        const int q  = tid >> 10;          // layer*12 + wv*3 + nt
        const int nt = q % 3;
        const int wv_ = (q / 3) & 3;
        const int layer = q / 12;
        const int col = nt * 64 + wv_ * 16 + (l & 15);
        const int hb  = ks * 32 + (l >> 4) * 8 + e;
        const float val = w2[layer * 64 * 192 + hb * 192 + col] * (1.0f / 127.0f);
        w2frag[tid] = (short)f2bf(val);
    }
    const int tid2 = tid - NFRAG;
    if (tid2 >= 0 && tid2 < 16384) {
        const int ff = tid2 & 63;
        const int g  = (tid2 >> 6) & 63;
        const int m  = (tid2 >> 12) & 1;
        const int layer = tid2 >> 13;
        const float* src = (m == 0 ? ws : wv) + layer * 4096;
        wT[tid2] = src[ff * 64 + g];
    }
}

// -------------------- init: s = embed[species] + glob @ glob_w -------------
__global__ __launch_bounds__(256) void init_kernel(
    const int* __restrict__ species, const float* __restrict__ glob,
    const float* __restrict__ embed, const float* __restrict__ glob_w,
    float* __restrict__ s)
{
    const int node = blockIdx.x * 4 + (threadIdx.x >> 6);   // b*128 + n
    const int b = node >> 7;
    const int f = threadIdx.x & 63;
    const int sp = species[node];
    float acc = embed[sp * FF + f];
#pragma unroll
    for (int k = 0; k < 16; ++k)
        acc = fmaf(glob[b * 16 + k], glob_w[k * FF + f], acc);
    s[node * FF + f] = acc;
}

// -------------------- fused message+agg+update (+readout for LAYER==1) ----
// grid (128 receivers, 32 batch), block 256 = 4 waves.
// wave w owns channels f in [16w, 16w+16).
template<int LAYER>
__global__ __launch_bounds__(256, 4) void msg_kernel(
    const float* __restrict__ pos,     // [B][N][3]
    const float* __restrict__ s_in,    // [B][N][F]
    const float* __restrict__ v_in,    // [B][N][F][4]  (unused when LAYER==0)
    const float* __restrict__ w1,      // [8][64]
    const float* __restrict__ b1,      // [64]
    const short* __restrict__ w2frag,  // [4][3][2][64][8] bf16 (layer slice)
    const float* __restrict__ wT,      // [2][64][64] (ws^T, wv^T; layer slice)
    const float* __restrict__ wout,    // [64]
    const float* __restrict__ scale,   // [1]
    float* __restrict__ s_out,         // LAYER==0 only
    float* __restrict__ v_out,         // LAYER==0 only, [B][N][F][4]
    float* __restrict__ out)           // LAYER==1 only
{
    __shared__ unsigned short hid_lds[NN * 64];   // 16 KB, XOR-swizzled rows
    __shared__ float4 unit_lds[NN];
    __shared__ float4 phiA[NN], phiB[NN];
    __shared__ float agg_lds[4][64];

    const int i = blockIdx.x;
    const int b = blockIdx.y;
    const int t = threadIdx.x;
    const int w = t >> 6;          // wave
    const int l = t & 63;          // lane
    const int node = b * NN + i;
    const float* pb = pos + b * NN * 3;

    // ---- B fragments: pre-baked, 6 coalesced 16B loads (hide under A1/A2) --
    short8 bfrag[3][2];
    {
        const short8* wf = (const short8*)w2frag;
#pragma unroll
        for (int nt = 0; nt < 3; ++nt)
#pragma unroll
            for (int ks = 0; ks < 2; ++ks)
                bfrag[nt][ks] = wf[((w * 3 + nt) * 2 + ks) * 64 + l];
    }

    // ---- phase A1: per-edge distance, unit vector, and RBF (once per j) ---
    if (t < NN) {
        const int j = t;
        const float dx = pb[i * 3 + 0] - pb[j * 3 + 0];
        const float dy = pb[i * 3 + 1] - pb[j * 3 + 1];
        const float dz = pb[i * 3 + 2] - pb[j * 3 + 2];
        const float d2 = fmaf(dx, dx, fmaf(dy, dy, fmaf(dz, dz, 1e-12f)));
        const float inv = __builtin_amdgcn_rsqf(d2);
        const float dd = d2 * inv;
        unit_lds[j] = make_float4(dx * inv, dy * inv, dz * inv, 0.0f);
        float ph[8];
#pragma unroll
        for (int r = 0; r < 8; ++r) {
            const float td = dd - (float)r * (5.0f / 7.0f);
            ph[r] = __expf(td * td * -1.28f);   // 1/(2*0.625^2) = 1.28
        }
        phiA[j] = make_float4(ph[0], ph[1], ph[2], ph[3]);
        phiB[j] = make_float4(ph[4], ph[5], ph[6], ph[7]);
    }
    __syncthreads();

    // ---- phase A2: hid[j][h] = silu(phi(d_j) @ W1 + b1), bf16 -> LDS ----
    {
        const int h0 = (t & 7) * 8;    // h-chunk (8 units)
        const int jb = t >> 3;         // 0..31
        float w1r[8][8];
#pragma unroll
        for (int r = 0; r < 8; ++r) {
            const float4 a0 = *(const float4*)(w1 + r * 64 + h0);
            const float4 a1 = *(const float4*)(w1 + r * 64 + h0 + 4);
            w1r[r][0] = a0.x; w1r[r][1] = a0.y; w1r[r][2] = a0.z; w1r[r][3] = a0.w;
            w1r[r][4] = a1.x; w1r[r][5] = a1.y; w1r[r][6] = a1.z; w1r[r][7] = a1.w;
        }
        float b1r[8];
        {
            const float4 c0 = *(const float4*)(b1 + h0);
            const float4 c1 = *(const float4*)(b1 + h0 + 4);
            b1r[0] = c0.x; b1r[1] = c0.y; b1r[2] = c0.z; b1r[3] = c0.w;
            b1r[4] = c1.x; b1r[5] = c1.y; b1r[6] = c1.z; b1r[7] = c1.w;
        }
#pragma unroll
        for (int it = 0; it < 4; ++it) {
            const int j = jb + it * 32;
            const float4 pA = phiA[j];
            const float4 pB = phiB[j];
            short8 hv;
#pragma unroll
            for (int e = 0; e < 8; ++e) {
                float acc = b1r[e];
                acc = fmaf(pA.x, w1r[0][e], acc);
                acc = fmaf(pA.y, w1r[1][e], acc);
                acc = fmaf(pA.z, w1r[2][e], acc);
                acc = fmaf(pA.w, w1r[3][e], acc);
                acc = fmaf(pB.x, w1r[4][e], acc);
                acc = fmaf(pB.y, w1r[5][e], acc);
                acc = fmaf(pB.z, w1r[6][e], acc);
                acc = fmaf(pB.w, w1r[7][e], acc);
                const float ex = __expf(-acc);
                const float sv = acc * __builtin_amdgcn_rcpf(1.0f + ex);
                hv[e] = (short)f2bf_fast(sv);
            }
            if (j == i) hv = (short8){0, 0, 0, 0, 0, 0, 0, 0};
            const int byte = j * 128 + ((h0 * 2) ^ ((j & 7) << 4));
            *(short8*)((char*)hid_lds + byte) = hv;
        }
    }
    __syncthreads();

    // ---- fused phase B+C: per 16-row j-tile, MFMA then consume ----
    const int f    = w * 16 + (l & 15);
    const int jsub = (l >> 4) * 4;
    const float* sb = s_in + b * NN * FF;
    const float4* vb4 = (LAYER > 0) ? ((const float4*)v_in) + b * NN * FF : nullptr;

    float accs = 0.f, av0 = 0.f, av1 = 0.f, av2 = 0.f;

    // prefetch tile 0's s/v into registers
    float sP[4]; float4 vP[4];
#pragma unroll
    for (int reg = 0; reg < 4; ++reg) {
        const int j = jsub + reg;
        sP[reg] = sb[j * FF + f];
        if (LAYER > 0) vP[reg] = vb4[j * FF + f];
    }

#pragma unroll
    for (int mt = 0; mt < 8; ++mt) {
        // a-fragments for this 16-row tile (both K-slices)
        const int jA = mt * 16 + (l & 15);
        const int base = jA * 128;
        const int sw = (jA & 7) << 4;
        const short8 a0 = *(const short8*)((const char*)hid_lds + base + (((l >> 4) * 16 +  0) ^ sw));
        const short8 a1 = *(const short8*)((const char*)hid_lds + base + (((l >> 4) * 16 + 64) ^ sw));

        f32x4 c0 = (f32x4){0.f, 0.f, 0.f, 0.f};
        f32x4 c1 = (f32x4){0.f, 0.f, 0.f, 0.f};
        f32x4 c2 = (f32x4){0.f, 0.f, 0.f, 0.f};
        c0 = __builtin_amdgcn_mfma_f32_16x16x32_bf16(a0, bfrag[0][0], c0, 0, 0, 0);
        c0 = __builtin_amdgcn_mfma_f32_16x16x32_bf16(a1, bfrag[0][1], c0, 0, 0, 0);
        c1 = __builtin_amdgcn_mfma_f32_16x16x32_bf16(a0, bfrag[1][0], c1, 0, 0, 0);
        c1 = __builtin_amdgcn_mfma_f32_16x16x32_bf16(a1, bfrag[1][1], c1, 0, 0, 0);
        c2 = __builtin_amdgcn_mfma_f32_16x16x32_bf16(a0, bfrag[2][0], c2, 0, 0, 0);
        c2 = __builtin_amdgcn_mfma_f32_16x16x32_bf16(a1, bfrag[2][1], c2, 0, 0, 0);

        // prefetch next tile's s/v while MFMAs are in flight
        float sN[4]; float4 vN[4];
        if (mt < 7) {
#pragma unroll
            for (int reg = 0; reg < 4; ++reg) {
                const int j = (mt + 1) * 16 + jsub + reg;
                sN[reg] = sb[j * FF + f];
                if (LAYER > 0) vN[reg] = vb4[j * FF + f];
            }
        }

        // consume this tile's messages (lane covers 4 j rows)
#pragma unroll
        for (int reg = 0; reg < 4; ++reg) {
            const int j  = mt * 16 + jsub + reg;
            const float r1 = c0[reg];
            const float r2 = c1[reg];
            const float r3 = c2[reg];
            const float sj = sP[reg];
            const float r3s = r3 * sj;
            const float4 u = unit_lds[j];
            accs = fmaf(r1, sj, accs);
            av0 = fmaf(r3s, u.x, av0);
            av1 = fmaf(r3s, u.y, av1);
            av2 = fmaf(r3s, u.z, av2);
            if (LAYER > 0) {
                av0 = fmaf(r2, vP[reg].x, av0);
                av1 = fmaf(r2, vP[reg].y, av1);
                av2 = fmaf(r2, vP[reg].z, av2);
            }
        }
#pragma unroll
        for (int reg = 0; reg < 4; ++reg) {
            sP[reg] = sN[reg];
            if (LAYER > 0) vP[reg] = vN[reg];
        }
    }

    accs += __shfl_xor(accs, 16, 64); accs += __shfl_xor(accs, 32, 64);
    av0  += __shfl_xor(av0, 16, 64);  av0  += __shfl_xor(av0, 32, 64);
    av1  += __shfl_xor(av1, 16, 64);  av1  += __shfl_xor(av1, 32, 64);
    av2  += __shfl_xor(av2, 16, 64);  av2  += __shfl_xor(av2, 32, 64);
    if (l < 16) {
        // 1/127 already folded into W2 fragments
        agg_lds[0][f] = accs;
        agg_lds[1][f] = av0;
        agg_lds[2][f] = av1;
        agg_lds[3][f] = av2;
    }
    __syncthreads();

    // ---- tail: node update (+ readout for last layer), transposed weights --
    const int g = l;
    if (LAYER == 0) {
        const float* wrow = wT + (w == 0 ? 0 : 4096) + g * 64;
        const float* ag   = (w == 0) ? agg_lds[0] : agg_lds[w];
        float a = (w == 0) ? s_in[node * FF + g] : 0.0f;
#pragma unroll
        for (int k = 0; k < 16; ++k) {
            const float4 w4 = ((const float4*)wrow)[k];
            const float4 a4 = ((const float4*)ag)[k];
            a = fmaf(a4.x, w4.x, a); a = fmaf(a4.y, w4.y, a);
            a = fmaf(a4.z, w4.z, a); a = fmaf(a4.w, w4.w, a);
        }
        if (w == 0) s_out[node * FF + g] = a;
        else        v_out[(node * FF + g) * 4 + (w - 1)] = a;
    } else {
        if (w > 0) {
            const int d = w - 1;
            const float* wrow = wT + 4096 + g * 64;
            const float* ag   = agg_lds[w];
            float a = v_in[(node * FF + g) * 4 + d];
#pragma unroll
            for (int k = 0; k < 16; ++k) {
                const float4 w4 = ((const float4*)wrow)[k];
                const float4 a4 = ((const float4*)ag)[k];
                a = fmaf(a4.x, w4.x, a); a = fmaf(a4.y, w4.y, a);
                a = fmaf(a4.z, w4.z, a); a = fmaf(a4.w, w4.w, a);
            }
            float p = a * wout[g];
#pragma unroll
            for (int off = 1; off < 64; off <<= 1)
                p += __shfl_xor(p, off, 64);
            if (l == 0)
                out[node * 3 + d] = (p - pos[node * 3 + d]) * scale[0];
        }
    }
}

extern "C" void kernel_launch(void* const* d_in, const int* in_sizes, int n_in,
                              void* d_out, int out_size, void* d_ws, size_t ws_size,
                              hipStream_t stream) {
    const float* pos     = (const float*)d_in[0];
    const int*   species = (const int*)  d_in[1];
    const float* glob    = (const float*)d_in[2];
    const float* embed   = (const float*)d_in[3];
    const float* glob_w  = (const float*)d_in[4];
    const float* rbf_w1  = (const float*)d_in[5];   // [2][8][64]
    const float* rbf_b1  = (const float*)d_in[6];   // [2][64]
    const float* rbf_w2  = (const float*)d_in[7];   // [2][64][192]
    const float* ws      = (const float*)d_in[8];   // [2][64][64]
    const float* wv      = (const float*)d_in[9];   // [2][64][64]
    const float* wout    = (const float*)d_in[10];  // [64]
    const float* scale   = (const float*)d_in[11];  // [1]

    float* wsf = (float*)d_ws;
    float* s0     = wsf;                   // 262144 floats
    float* s1     = wsf + 262144;          // 262144
    float* v1     = wsf + 524288;          // 1048576
    short* w2frag = (short*)(wsf + 1572864);   // 24576 shorts (12288 floats)
    float* wT     = wsf + 1572864 + 12288;     // 16384 floats
    float* outp = (float*)d_out;

    prep_kernel<<<dim3(160), 256, 0, stream>>>(rbf_w2, ws, wv, w2frag, wT);
    init_kernel<<<dim3(BB * NN / 4), 256, 0, stream>>>(species, glob, embed, glob_w, s0);

    msg_kernel<0><<<dim3(NN, BB), 256, 0, stream>>>(
        pos, s0, nullptr,
        rbf_w1, rbf_b1, w2frag, wT, wout, scale,
        s1, v1, nullptr);

    msg_kernel<1><<<dim3(NN, BB), 256, 0, stream>>>(
        pos, s1, v1,
        rbf_w1 + 8 * 64, rbf_b1 + 64, w2frag + 12288, wT + 8192, wout, scale,
        nullptr, nullptr, outp);
}